// Round 6
// baseline (751.780 us; speedup 1.0000x reference)
//
#include <hip/hip_runtime.h>
#include <hip/hip_bf16.h>

typedef __hip_bfloat16 bf16;
typedef __attribute__((ext_vector_type(8))) short short8;
typedef __attribute__((ext_vector_type(4))) float float4v;

// ---- problem constants ----
#define N1 120000
#define N2 20000
#define N3 4000
#define E0 1800000
#define E1 200000
#define E2 20000
#define D_IN 128
#define D_HID 256
#define D_OUT 47
#define CAP 64           // padded-CSR slots per dst (max Poisson degree ~38)

// fused-prep geometry
#define QF0 (E0 / 4)                       // 450000 edge-quads layer0
#define QF1 (E1 / 4)                       //  50000
#define QF2 (E2 / 4)                       //   5000
#define FILLB ((QF0 + QF1 + QF2 + 255) / 256)  // 1973
#define CONVB (400000 * D_IN / 8 / 256)        // 25000 (exact)
#define WTB (221184 / 256)                     // 864 (exact)

__device__ __forceinline__ void stv(float* p, float v) { *p = v; }
__device__ __forceinline__ void stv(bf16* p, float v) { *p = __float2bfloat16(v); }

__device__ __forceinline__ unsigned short f2bu(float v) {
    union { bf16 h; unsigned short u; } c;
    c.h = __float2bfloat16(v);
    return c.u;
}
__device__ __forceinline__ short f2bs(float v) { return (short)f2bu(v); }
__device__ __forceinline__ float bu2f(unsigned short u) { return __uint_as_float(((unsigned)u) << 16); }

__device__ __forceinline__ short8 load8(const bf16* p) {
    union { uint4 u; short8 s; } r;
    r.u = *(const uint4*)p;
    return r.s;
}
__device__ __forceinline__ short8 load8(const float* p) {
    float4 a = *(const float4*)p;
    float4 b = *(const float4*)(p + 4);
    short8 s;
    s[0] = f2bs(a.x); s[1] = f2bs(a.y); s[2] = f2bs(a.z); s[3] = f2bs(a.w);
    s[4] = f2bs(b.x); s[5] = f2bs(b.y); s[6] = f2bs(b.z); s[7] = f2bs(b.w);
    return s;
}

// ================= fused prep: fill_pad (first) + convert_x + wt_batch ======
// Independent jobs dispatched by blockIdx range. Fill blocks go FIRST: they
// are the long pole (atomic-throughput bound, ~90% idle issue slots) and
// ~fully occupy the machine; convert/wt blocks stream in behind them and
// execute in the idle slots, hiding their serial time under the fill.
__global__ __launch_bounds__(256) void prep(
    const float* __restrict__ x, bf16* __restrict__ xb,
    const float* __restrict__ W0s, const float* __restrict__ W0n,
    const float* __restrict__ W1s, const float* __restrict__ W1n,
    const float* __restrict__ W2s, const float* __restrict__ W2n,
    bf16* __restrict__ T0s, bf16* __restrict__ T0n, bf16* __restrict__ T1s,
    bf16* __restrict__ T1n, bf16* __restrict__ T2s, bf16* __restrict__ T2n,
    const int* __restrict__ s0, const int* __restrict__ d0,
    const int* __restrict__ s1, const int* __restrict__ d1,
    const int* __restrict__ s2, const int* __restrict__ d2,
    int* __restrict__ c0, int* __restrict__ c1, int* __restrict__ c2,
    int* __restrict__ col0, int* __restrict__ col1, int* __restrict__ col2) {
    int b = blockIdx.x;
    if (b < FILLB) {
        // ---- padded-CSR fill, 4 edges/thread (independent atomic chains) ----
        int t = b * 256 + threadIdx.x;
        const int* s; const int* d; int* c; int* col;
        if (t < QF0)             { s = s0; d = d0; c = c0; col = col0; }
        else if (t < QF0 + QF1)  { s = s1; d = d1; c = c1; col = col1; t -= QF0; }
        else if (t < QF0 + QF1 + QF2) { s = s2; d = d2; c = c2; col = col2; t -= QF0 + QF1; }
        else return;
        int4 sv = *(const int4*)(s + 4 * t);
        int4 dv = *(const int4*)(d + 4 * t);
        int p0 = atomicAdd(&c[dv.x], 1);
        int p1 = atomicAdd(&c[dv.y], 1);
        int p2 = atomicAdd(&c[dv.z], 1);
        int p3 = atomicAdd(&c[dv.w], 1);
        if (p0 < CAP) col[((size_t)dv.x << 6) + p0] = sv.x;
        if (p1 < CAP) col[((size_t)dv.y << 6) + p1] = sv.y;
        if (p2 < CAP) col[((size_t)dv.z << 6) + p2] = sv.z;
        if (p3 < CAP) col[((size_t)dv.w << 6) + p3] = sv.w;
    } else if (b < FILLB + CONVB) {
        // ---- x -> bf16 conversion, 8 floats/thread ----
        int i = (b - FILLB) * 256 + threadIdx.x;   // < 6,400,000 exact
        const float* p = x + (size_t)i * 8;
        float4 a = *(const float4*)p;
        float4 bb = *(const float4*)(p + 4);
        union { uint4 u; short sh[8]; } o;
        o.sh[0] = f2bs(a.x);  o.sh[1] = f2bs(a.y);  o.sh[2] = f2bs(a.z);  o.sh[3] = f2bs(a.w);
        o.sh[4] = f2bs(bb.x); o.sh[5] = f2bs(bb.y); o.sh[6] = f2bs(bb.z); o.sh[7] = f2bs(bb.w);
        *(uint4*)(xb + (size_t)i * 8) = o.u;
    } else {
        // ---- weight transpose+convert ----
        int i = (b - FILLB - CONVB) * 256 + threadIdx.x;  // < 221184 exact
        const float* Wm; bf16* T; int K, N, j;
        if      (i <  32768) { Wm = W0s; T = T0s; K = 128; N = 256; j = i; }
        else if (i <  65536) { Wm = W0n; T = T0n; K = 128; N = 256; j = i - 32768; }
        else if (i < 131072) { Wm = W1s; T = T1s; K = 256; N = 256; j = i - 65536; }
        else if (i < 196608) { Wm = W1n; T = T1n; K = 256; N = 256; j = i - 131072; }
        else if (i < 208896) { Wm = W2s; T = T2s; K = 256; N = 47;  j = i - 196608; }
        else                 { Wm = W2n; T = T2n; K = 256; N = 47;  j = i - 208896; }
        int n = j / K, k = j - n * K;
        float v = (n < N) ? Wm[(size_t)k * N + n] : 0.f;
        T[j] = __float2bfloat16(v);
    }
}

// ================= small-workspace fallbacks (separate kernels) =============
__global__ void wt_batch(const float* W0s, const float* W0n, const float* W1s,
                         const float* W1n, const float* W2s, const float* W2n,
                         bf16* T0s, bf16* T0n, bf16* T1s, bf16* T1n, bf16* T2s, bf16* T2n) {
    int i = blockIdx.x * blockDim.x + threadIdx.x;
    const float* W; bf16* T; int K, N, j;
    if      (i <  32768) { W = W0s; T = T0s; K = 128; N = 256; j = i; }
    else if (i <  65536) { W = W0n; T = T0n; K = 128; N = 256; j = i - 32768; }
    else if (i < 131072) { W = W1s; T = T1s; K = 256; N = 256; j = i - 65536; }
    else if (i < 196608) { W = W1n; T = T1n; K = 256; N = 256; j = i - 131072; }
    else if (i < 208896) { W = W2s; T = T2s; K = 256; N = 47;  j = i - 196608; }
    else if (i < 221184) { W = W2n; T = T2n; K = 256; N = 47;  j = i - 208896; }
    else return;
    int n = j / K, k = j - n * K;
    float v = (n < N) ? W[(size_t)k * N + n] : 0.f;
    T[j] = __float2bfloat16(v);
}

__global__ void fill_pad(const int* __restrict__ s0, const int* __restrict__ d0,
                         const int* __restrict__ s1, const int* __restrict__ d1,
                         const int* __restrict__ s2, const int* __restrict__ d2,
                         int* __restrict__ c0, int* __restrict__ c1, int* __restrict__ c2,
                         int* __restrict__ col0, int* __restrict__ col1,
                         int* __restrict__ col2) {
    int i = blockIdx.x * blockDim.x + threadIdx.x;
    if (i < E0) {
        int d = d0[i];
        int p = atomicAdd(&c0[d], 1);
        if (p < CAP) col0[((size_t)d << 6) + p] = s0[i];
    } else if (i < E0 + E1) {
        int e = i - E0; int d = d1[e];
        int p = atomicAdd(&c1[d], 1);
        if (p < CAP) col1[((size_t)d << 6) + p] = s1[e];
    } else if (i < E0 + E1 + E2) {
        int e = i - E0 - E1; int d = d2[e];
        int p = atomicAdd(&c2[d], 1);
        if (p < CAP) col2[((size_t)d << 6) + p] = s2[e];
    }
}

// ================= gather-mean over padded CSR, scalar float fallback =======
template <int DIN>
__global__ __launch_bounds__(256) void gather_pad_f(const float* __restrict__ h,
        const int* __restrict__ cn, const int* __restrict__ col,
        int n_dst, bf16* __restrict__ agg) {
    int gw = (blockIdx.x * blockDim.x + threadIdx.x) >> 6;
    int lane = threadIdx.x & 63;
    if (gw >= n_dst) return;
    int deg = cn[gw];
    int beg = gw << 6, end = beg + min(deg, CAP);
    constexpr int VP = DIN / 64;
    float s[VP] = {};
    for (int e = beg; e < end; ++e) {
        const float* hp = h + (size_t)col[e] * DIN + lane * VP;
        float2 v = *(const float2*)hp;
        s[0] += v.x; s[1] += v.y;
    }
    float inv = 1.f / fmaxf((float)deg, 1.f);
    ushort2 o; o.x = f2bu(s[0] * inv); o.y = f2bu(s[1] * inv);
    *(ushort2*)(agg + (size_t)gw * DIN + lane * VP) = o;
}

// ================= gather-mean over padded CSR, wide bf16 path ==============
// One wave per dst node; G = DIN/8 lanes per row (16B/lane), R = 64/G rows in
// flight per load instruction; shfl_xor butterfly combines the R groups.
template <int DIN>
__global__ __launch_bounds__(256) void gather_pad_w(const bf16* __restrict__ h,
        const int* __restrict__ cn, const int* __restrict__ col,
        int n_dst, bf16* __restrict__ agg) {
    constexpr int G = DIN / 8;
    constexpr int R = 64 / G;
    int gw = (blockIdx.x * blockDim.x + threadIdx.x) >> 6;
    int lane = threadIdx.x & 63;
    if (gw >= n_dst) return;
    int deg = cn[gw];
    int beg = gw << 6, end = beg + min(deg, CAP);
    int g = lane / G;
    int p = lane & (G - 1);

    float s[8] = {};
    auto accum = [&](const short8& v) {
        #pragma unroll
        for (int j = 0; j < 8; j++) s[j] += bu2f((unsigned short)v[j]);
    };

    int e = beg;
    for (; e + 2 * R <= end; e += 2 * R) {
        int sa = col[e + g];
        int sb = col[e + R + g];
        short8 va = load8(h + (size_t)sa * DIN + p * 8);
        short8 vb = load8(h + (size_t)sb * DIN + p * 8);
        accum(va); accum(vb);
    }
    for (; e + R <= end; e += R) {
        int sa = col[e + g];
        short8 va = load8(h + (size_t)sa * DIN + p * 8);
        accum(va);
    }
    if (e < end) {
        bool act = (e + g) < end;
        int sa = col[act ? (e + g) : beg];
        short8 va = load8(h + (size_t)sa * DIN + p * 8);
        if (act) accum(va);
    }

    #pragma unroll
    for (int m = G; m < 64; m <<= 1) {
        #pragma unroll
        for (int j = 0; j < 8; j++) s[j] += __shfl_xor(s[j], m, 64);
    }

    float inv = 1.f / fmaxf((float)deg, 1.f);
    if (g == 0) {
        union { uint4 u; unsigned short us[8]; } o;
        #pragma unroll
        for (int j = 0; j < 8; j++) o.us[j] = f2bu(s[j] * inv);
        *(uint4*)(agg + (size_t)gw * DIN + p * 8) = o.u;
    }
}

// ================= fused MFMA SAGE GEMM (register-staged, R3-proven) ========
// C[M,Nstore] = relu?( A@Ws + Mn@Wn + b ) as K-concatenated bf16 MFMA GEMM.
// Block tile 128x128, 4 waves of 64x64, 16x16x32 MFMA, BK=32, LDS [128][48].
template <typename TA, typename TC, bool RELU>
__global__ __launch_bounds__(256) void gemm_mfma(
    const TA* __restrict__ A, const bf16* __restrict__ Mn,
    const bf16* __restrict__ Wst, const bf16* __restrict__ Wnt,
    const float* __restrict__ bias, TC* __restrict__ C,
    int M, int Nstore, int Npad, int K) {
    __shared__ short As[128][48];
    __shared__ short Bs[128][48];

    int tid = threadIdx.x;
    int m0 = blockIdx.x * 128;
    int n0 = blockIdx.y * 128;
    int lane = tid & 63, wid = tid >> 6;
    int wm = (wid & 1) * 64, wn = (wid >> 1) * 64;
    int l15 = lane & 15, quad = lane >> 4;

    float4v acc[4][4] = {};

    int nsteps = (2 * K) >> 5;
    int r = tid >> 2, c = (tid & 3) << 3;
    for (int s = 0; s < nsteps; ++s) {
        int ks = s << 5;
        bool self = ks < K;
        int ko = self ? ks : ks - K;
        #pragma unroll
        for (int it = 0; it < 2; ++it) {
            int rr = r + it * 64;
            {
                int gm = m0 + rr;
                short8 v = (short8)0;
                if (gm < M) {
                    if (self) v = load8(A  + (size_t)gm * K + ko + c);
                    else      v = load8(Mn + (size_t)gm * K + ko + c);
                }
                *(short8*)&As[rr][c] = v;
            }
            {
                int gn = n0 + rr;
                short8 w = (short8)0;
                if (gn < Npad) {
                    const bf16* Wp = self ? Wst : Wnt;
                    w = load8(Wp + (size_t)gn * K + ko + c);
                }
                *(short8*)&Bs[rr][c] = w;
            }
        }
        __syncthreads();
        short8 af[4], bfr[4];
        #pragma unroll
        for (int i = 0; i < 4; ++i)
            af[i] = *(const short8*)&As[wm + i * 16 + l15][quad * 8];
        #pragma unroll
        for (int j = 0; j < 4; ++j)
            bfr[j] = *(const short8*)&Bs[wn + j * 16 + l15][quad * 8];
        #pragma unroll
        for (int i = 0; i < 4; ++i)
            #pragma unroll
            for (int j = 0; j < 4; ++j)
                acc[i][j] = __builtin_amdgcn_mfma_f32_16x16x32_bf16(af[i], bfr[j], acc[i][j], 0, 0, 0);
        __syncthreads();
    }

    #pragma unroll
    for (int i = 0; i < 4; ++i) {
        #pragma unroll
        for (int j = 0; j < 4; ++j) {
            int gn = n0 + wn + j * 16 + l15;
            if (gn >= Nstore) continue;
            float bv = bias[gn];
            #pragma unroll
            for (int rr = 0; rr < 4; ++rr) {
                int gm = m0 + wm + i * 16 + quad * 4 + rr;
                if (gm >= M) continue;
                float v = acc[i][j][rr] + bv;
                if (RELU) v = fmaxf(v, 0.f);
                stv(&C[(size_t)gm * Nstore + gn], v);
            }
        }
    }
}

// ================= launch =================
extern "C" void kernel_launch(void* const* d_in, const int* in_sizes, int n_in,
                              void* d_out, int out_size, void* d_ws, size_t ws_size,
                              hipStream_t stream) {
    const float* x    = (const float*)d_in[0];
    const int*  src0 = (const int*)d_in[1];
    const int*  dst0 = (const int*)d_in[2];
    const int*  src1 = (const int*)d_in[3];
    const int*  dst1 = (const int*)d_in[4];
    const int*  src2 = (const int*)d_in[5];
    const int*  dst2 = (const int*)d_in[6];
    const float* Ws0 = (const float*)d_in[7];
    const float* Wn0 = (const float*)d_in[8];
    const float* b0  = (const float*)d_in[9];
    const float* Ws1 = (const float*)d_in[10];
    const float* Wn1 = (const float*)d_in[11];
    const float* b1  = (const float*)d_in[12];
    const float* Ws2 = (const float*)d_in[13];
    const float* Wn2 = (const float*)d_in[14];
    const float* b2  = (const float*)d_in[15];
    float* out = (float*)d_out;

    char* W = (char*)d_ws;
    // ---- persistent block: cnt + padded col + weights ----
    int* cnt0  = (int*)(W + 0);              //   480,000
    int* cnt1  = (int*)(W + 480000);         //    80,000
    int* cnt2  = (int*)(W + 560000);         //    16,000  (memset [0,576,000))
    int* col0  = (int*)(W + 576000);         // 30,720,000 (120000 x 64)
    int* col1  = (int*)(W + 31296000);       //  5,120,000 (20000 x 64)
    int* col2  = (int*)(W + 36416000);       //  1,024,000 (4000 x 64)
    bf16* Wst0 = (bf16*)(W + 37440000);      //     65,536 (256 x 128)
    bf16* Wnt0 = (bf16*)(W + 37505536);      //     65,536
    bf16* Wst1 = (bf16*)(W + 37571072);      //    131,072 (256 x 256)
    bf16* Wnt1 = (bf16*)(W + 37702144);      //    131,072
    bf16* Wst2 = (bf16*)(W + 37833216);      //     24,576 (48 x 256, zero-padded)
    bf16* Wnt2 = (bf16*)(W + 37857792);      //     24,576  (end 37,882,368)

    const size_t BASE = 37882368;
    // big path: + xb(102,400,000) + agg0(30,720,000) + h1(61,440,000) = 232,442,368
    const bool big = ws_size >= (size_t)233000000;
    bf16* xb   = (bf16*)(W + BASE);                                // big only
    size_t o   = BASE + (big ? 102400000 : 0);
    bf16* agg0 = (bf16*)(W + o);                                   // 30,720,000
    bf16* h1   = (bf16*)(W + o + 30720000);                        // 61,440,000
    bf16* agg1 = (bf16*)(W + BASE);                                // 10,240,000 (xb/agg0 dead)
    bf16* h2   = (bf16*)(W + BASE + 10240000);                     // 10,240,000
    bf16* agg2 = (bf16*)(W + BASE + 20480000);                     //  2,048,000

    // ---- phase 1: fused prep (big) or separate kernels (small) ----
    hipMemsetAsync(W, 0, 576000, stream);  // all three cnt arrays
    const int ETOT = E0 + E1 + E2;
    if (big) {
        prep<<<FILLB + CONVB + WTB, 256, 0, stream>>>(
            x, xb, Ws0, Wn0, Ws1, Wn1, Ws2, Wn2,
            Wst0, Wnt0, Wst1, Wnt1, Wst2, Wnt2,
            src0, dst0, src1, dst1, src2, dst2,
            cnt0, cnt1, cnt2, col0, col1, col2);
    } else {
        wt_batch<<<(221184 + 255) / 256, 256, 0, stream>>>(Ws0, Wn0, Ws1, Wn1, Ws2, Wn2,
                                                           Wst0, Wnt0, Wst1, Wnt1, Wst2, Wnt2);
        fill_pad<<<(ETOT + 255) / 256, 256, 0, stream>>>(src0, dst0, src1, dst1, src2, dst2,
                                                         cnt0, cnt1, cnt2, col0, col1, col2);
    }

    // ---- layer 0: 400000 -> 120000, K=128, relu ----
    if (big) {
        gather_pad_w<D_IN><<<(N1 + 3) / 4, 256, 0, stream>>>(xb, cnt0, col0, N1, agg0);
        dim3 grid((N1 + 127) / 128, 2);
        gemm_mfma<bf16, bf16, true><<<grid, 256, 0, stream>>>(xb, agg0, Wst0, Wnt0, b0, h1, N1, 256, 256, 128);
    } else {
        gather_pad_f<D_IN><<<(N1 + 3) / 4, 256, 0, stream>>>(x, cnt0, col0, N1, agg0);
        dim3 grid((N1 + 127) / 128, 2);
        gemm_mfma<float, bf16, true><<<grid, 256, 0, stream>>>(x, agg0, Wst0, Wnt0, b0, h1, N1, 256, 256, 128);
    }

    // ---- layer 1: 120000 -> 20000, K=256, relu ----
    gather_pad_w<D_HID><<<(N2 + 3) / 4, 256, 0, stream>>>(h1, cnt1, col1, N2, agg1);
    {
        dim3 grid((N2 + 127) / 128, 2);
        gemm_mfma<bf16, bf16, true><<<grid, 256, 0, stream>>>(h1, agg1, Wst1, Wnt1, b1, h2, N2, 256, 256, 256);
    }

    // ---- layer 2: 20000 -> 4000, K=256, no relu ----
    gather_pad_w<D_HID><<<(N3 + 3) / 4, 256, 0, stream>>>(h2, cnt2, col2, N3, agg2);
    {
        dim3 grid((N3 + 127) / 128, 1);
        gemm_mfma<bf16, float, false><<<grid, 256, 0, stream>>>(h2, agg2, Wst2, Wnt2, b2, out, N3, 47, 48, 256);
    }
}

// Round 8
// 672.261 us; speedup vs baseline: 1.1183x; 1.1183x over previous
//
#include <hip/hip_runtime.h>
#include <hip/hip_bf16.h>

typedef __hip_bfloat16 bf16;
typedef __attribute__((ext_vector_type(8))) short short8;
typedef __attribute__((ext_vector_type(4))) float float4v;

// ---- problem constants ----
#define N1 120000
#define N2 20000
#define N3 4000
#define E0 1800000
#define E1 200000
#define E2 20000
#define D_IN 128
#define D_HID 256
#define D_OUT 47
#define CAP 64           // padded-CSR slots per dst (max Poisson degree ~38)
// counters padded to one 64B line each: cnt index = dst*16
#define CSTR 16

__device__ __forceinline__ void stv(float* p, float v) { *p = v; }
__device__ __forceinline__ void stv(bf16* p, float v) { *p = __float2bfloat16(v); }

__device__ __forceinline__ unsigned short f2bu(float v) {
    union { bf16 h; unsigned short u; } c;
    c.h = __float2bfloat16(v);
    return c.u;
}
__device__ __forceinline__ short f2bs(float v) { return (short)f2bu(v); }
__device__ __forceinline__ float bu2f(unsigned short u) { return __uint_as_float(((unsigned)u) << 16); }

__device__ __forceinline__ short8 load8(const bf16* p) {
    union { uint4 u; short8 s; } r;
    r.u = *(const uint4*)p;
    return r.s;
}
__device__ __forceinline__ short8 load8(const float* p) {
    float4 a = *(const float4*)p;
    float4 b = *(const float4*)(p + 4);
    short8 s;
    s[0] = f2bs(a.x); s[1] = f2bs(a.y); s[2] = f2bs(a.z); s[3] = f2bs(a.w);
    s[4] = f2bs(b.x); s[5] = f2bs(b.y); s[6] = f2bs(b.z); s[7] = f2bs(b.w);
    return s;
}

// ================= x -> bf16 conversion =================
__global__ __launch_bounds__(256) void convert_x(const float* __restrict__ x,
                                                 bf16* __restrict__ xb, int n8) {
    int i = blockIdx.x * blockDim.x + threadIdx.x;
    if (i >= n8) return;
    const float* p = x + (size_t)i * 8;
    float4 a = *(const float4*)p;
    float4 b = *(const float4*)(p + 4);
    union { uint4 u; short s[8]; } o;
    o.s[0] = f2bs(a.x); o.s[1] = f2bs(a.y); o.s[2] = f2bs(a.z); o.s[3] = f2bs(a.w);
    o.s[4] = f2bs(b.x); o.s[5] = f2bs(b.y); o.s[6] = f2bs(b.z); o.s[7] = f2bs(b.w);
    *(uint4*)(xb + (size_t)i * 8) = o.u;
}

// ================= batched weight transpose+convert =================
// W[K][N] f32 -> Wt[Npad][K] bf16 (layer2 padded to 48 rows)
__global__ void wt_batch(const float* W0s, const float* W0n, const float* W1s,
                         const float* W1n, const float* W2s, const float* W2n,
                         bf16* T0s, bf16* T0n, bf16* T1s, bf16* T1n, bf16* T2s, bf16* T2n) {
    int i = blockIdx.x * blockDim.x + threadIdx.x;
    const float* W; bf16* T; int K, N, j;
    if      (i <  32768) { W = W0s; T = T0s; K = 128; N = 256; j = i; }
    else if (i <  65536) { W = W0n; T = T0n; K = 128; N = 256; j = i - 32768; }
    else if (i < 131072) { W = W1s; T = T1s; K = 256; N = 256; j = i - 65536; }
    else if (i < 196608) { W = W1n; T = T1n; K = 256; N = 256; j = i - 131072; }
    else if (i < 208896) { W = W2s; T = T2s; K = 256; N = 47;  j = i - 196608; }
    else if (i < 221184) { W = W2n; T = T2n; K = 256; N = 47;  j = i - 208896; }
    else return;
    int n = j / K, k = j - n * K;
    float v = (n < N) ? W[(size_t)k * N + n] : 0.f;
    T[j] = __float2bfloat16(v);
}

// ================= padded-CSR build: ONE atomic scatter pass ================
// col[d*CAP + p] = src, p from per-dst counter (padded to its own 64B line).
// cnt[d*CSTR] keeps the TRUE degree for the mean; p >= CAP writes dropped
// (probability ~0 for Poisson(15) over 120K nodes; memory-safety guard only).
__global__ void fill_pad(const int* __restrict__ s0, const int* __restrict__ d0,
                         const int* __restrict__ s1, const int* __restrict__ d1,
                         const int* __restrict__ s2, const int* __restrict__ d2,
                         int* __restrict__ c0, int* __restrict__ c1, int* __restrict__ c2,
                         int* __restrict__ col0, int* __restrict__ col1,
                         int* __restrict__ col2) {
    int i = blockIdx.x * blockDim.x + threadIdx.x;
    if (i < E0) {
        int d = d0[i];
        int p = atomicAdd(&c0[(size_t)d * CSTR], 1);
        if (p < CAP) col0[((size_t)d << 6) + p] = s0[i];
    } else if (i < E0 + E1) {
        int e = i - E0; int d = d1[e];
        int p = atomicAdd(&c1[(size_t)d * CSTR], 1);
        if (p < CAP) col1[((size_t)d << 6) + p] = s1[e];
    } else if (i < E0 + E1 + E2) {
        int e = i - E0 - E1; int d = d2[e];
        int p = atomicAdd(&c2[(size_t)d * CSTR], 1);
        if (p < CAP) col2[((size_t)d << 6) + p] = s2[e];
    }
}

// ================= gather-mean over padded CSR, scalar float fallback =======
template <int DIN>
__global__ __launch_bounds__(256) void gather_pad_f(const float* __restrict__ h,
        const int* __restrict__ cn, const int* __restrict__ col,
        int n_dst, bf16* __restrict__ agg) {
    int gw = (blockIdx.x * blockDim.x + threadIdx.x) >> 6;
    int lane = threadIdx.x & 63;
    if (gw >= n_dst) return;
    int deg = cn[(size_t)gw * CSTR];
    int beg = gw << 6, end = beg + min(deg, CAP);
    constexpr int VP = DIN / 64;
    float s[VP] = {};
    for (int e = beg; e < end; ++e) {
        const float* hp = h + (size_t)col[e] * DIN + lane * VP;
        float2 v = *(const float2*)hp;
        s[0] += v.x; s[1] += v.y;
    }
    float inv = 1.f / fmaxf((float)deg, 1.f);
    ushort2 o; o.x = f2bu(s[0] * inv); o.y = f2bu(s[1] * inv);
    *(ushort2*)(agg + (size_t)gw * DIN + lane * VP) = o;
}

// ================= gather-mean over padded CSR, wide bf16 path ==============
// One wave per dst node; G = DIN/8 lanes per row (16B/lane), R = 64/G rows in
// flight per load instruction; shfl_xor butterfly combines the R groups.
template <int DIN>
__global__ __launch_bounds__(256) void gather_pad_w(const bf16* __restrict__ h,
        const int* __restrict__ cn, const int* __restrict__ col,
        int n_dst, bf16* __restrict__ agg) {
    constexpr int G = DIN / 8;
    constexpr int R = 64 / G;
    int gw = (blockIdx.x * blockDim.x + threadIdx.x) >> 6;
    int lane = threadIdx.x & 63;
    if (gw >= n_dst) return;
    int deg = cn[(size_t)gw * CSTR];
    int beg = gw << 6, end = beg + min(deg, CAP);
    int g = lane / G;
    int p = lane & (G - 1);

    float s[8] = {};
    auto accum = [&](const short8& v) {
        #pragma unroll
        for (int j = 0; j < 8; j++) s[j] += bu2f((unsigned short)v[j]);
    };

    int e = beg;
    for (; e + 2 * R <= end; e += 2 * R) {
        int sa = col[e + g];
        int sb = col[e + R + g];
        short8 va = load8(h + (size_t)sa * DIN + p * 8);
        short8 vb = load8(h + (size_t)sb * DIN + p * 8);
        accum(va); accum(vb);
    }
    for (; e + R <= end; e += R) {
        int sa = col[e + g];
        short8 va = load8(h + (size_t)sa * DIN + p * 8);
        accum(va);
    }
    if (e < end) {
        bool act = (e + g) < end;
        int sa = col[act ? (e + g) : beg];
        short8 va = load8(h + (size_t)sa * DIN + p * 8);
        if (act) accum(va);
    }

    #pragma unroll
    for (int m = G; m < 64; m <<= 1) {
        #pragma unroll
        for (int j = 0; j < 8; j++) s[j] += __shfl_xor(s[j], m, 64);
    }

    float inv = 1.f / fmaxf((float)deg, 1.f);
    if (g == 0) {
        union { uint4 u; unsigned short us[8]; } o;
        #pragma unroll
        for (int j = 0; j < 8; j++) o.us[j] = f2bu(s[j] * inv);
        *(uint4*)(agg + (size_t)gw * DIN + p * 8) = o.u;
    }
}

// ================= fused MFMA SAGE GEMM (register-staged, R3-proven) ========
// C[M,Nstore] = relu?( A@Ws + Mn@Wn + b ) as K-concatenated bf16 MFMA GEMM.
// Block tile 128x128, 4 waves of 64x64, 16x16x32 MFMA, BK=32, LDS [128][48].
template <typename TA, typename TC, bool RELU>
__global__ __launch_bounds__(256) void gemm_mfma(
    const TA* __restrict__ A, const bf16* __restrict__ Mn,
    const bf16* __restrict__ Wst, const bf16* __restrict__ Wnt,
    const float* __restrict__ bias, TC* __restrict__ C,
    int M, int Nstore, int Npad, int K) {
    __shared__ short As[128][48];
    __shared__ short Bs[128][48];

    int tid = threadIdx.x;
    int m0 = blockIdx.x * 128;
    int n0 = blockIdx.y * 128;
    int lane = tid & 63, wid = tid >> 6;
    int wm = (wid & 1) * 64, wn = (wid >> 1) * 64;
    int l15 = lane & 15, quad = lane >> 4;

    float4v acc[4][4] = {};

    int nsteps = (2 * K) >> 5;
    int r = tid >> 2, c = (tid & 3) << 3;
    for (int s = 0; s < nsteps; ++s) {
        int ks = s << 5;
        bool self = ks < K;
        int ko = self ? ks : ks - K;
        #pragma unroll
        for (int it = 0; it < 2; ++it) {
            int rr = r + it * 64;
            {
                int gm = m0 + rr;
                short8 v = (short8)0;
                if (gm < M) {
                    if (self) v = load8(A  + (size_t)gm * K + ko + c);
                    else      v = load8(Mn + (size_t)gm * K + ko + c);
                }
                *(short8*)&As[rr][c] = v;
            }
            {
                int gn = n0 + rr;
                short8 w = (short8)0;
                if (gn < Npad) {
                    const bf16* Wp = self ? Wst : Wnt;
                    w = load8(Wp + (size_t)gn * K + ko + c);
                }
                *(short8*)&Bs[rr][c] = w;
            }
        }
        __syncthreads();
        short8 af[4], bfr[4];
        #pragma unroll
        for (int i = 0; i < 4; ++i)
            af[i] = *(const short8*)&As[wm + i * 16 + l15][quad * 8];
        #pragma unroll
        for (int j = 0; j < 4; ++j)
            bfr[j] = *(const short8*)&Bs[wn + j * 16 + l15][quad * 8];
        #pragma unroll
        for (int i = 0; i < 4; ++i)
            #pragma unroll
            for (int j = 0; j < 4; ++j)
                acc[i][j] = __builtin_amdgcn_mfma_f32_16x16x32_bf16(af[i], bfr[j], acc[i][j], 0, 0, 0);
        __syncthreads();
    }

    #pragma unroll
    for (int i = 0; i < 4; ++i) {
        #pragma unroll
        for (int j = 0; j < 4; ++j) {
            int gn = n0 + wn + j * 16 + l15;
            if (gn >= Nstore) continue;
            float bv = bias[gn];
            #pragma unroll
            for (int rr = 0; rr < 4; ++rr) {
                int gm = m0 + wm + i * 16 + quad * 4 + rr;
                if (gm >= M) continue;
                float v = acc[i][j][rr] + bv;
                if (RELU) v = fmaxf(v, 0.f);
                stv(&C[(size_t)gm * Nstore + gn], v);
            }
        }
    }
}

// ================= launch =================
extern "C" void kernel_launch(void* const* d_in, const int* in_sizes, int n_in,
                              void* d_out, int out_size, void* d_ws, size_t ws_size,
                              hipStream_t stream) {
    const float* x    = (const float*)d_in[0];
    const int*  src0 = (const int*)d_in[1];
    const int*  dst0 = (const int*)d_in[2];
    const int*  src1 = (const int*)d_in[3];
    const int*  dst1 = (const int*)d_in[4];
    const int*  src2 = (const int*)d_in[5];
    const int*  dst2 = (const int*)d_in[6];
    const float* Ws0 = (const float*)d_in[7];
    const float* Wn0 = (const float*)d_in[8];
    const float* b0  = (const float*)d_in[9];
    const float* Ws1 = (const float*)d_in[10];
    const float* Wn1 = (const float*)d_in[11];
    const float* b1  = (const float*)d_in[12];
    const float* Ws2 = (const float*)d_in[13];
    const float* Wn2 = (const float*)d_in[14];
    const float* b2  = (const float*)d_in[15];
    float* out = (float*)d_out;

    char* W = (char*)d_ws;
    // ---- persistent block: padded cnt + padded col + weights ----
    int* cnt0  = (int*)(W + 0);              //  7,680,000 (120000 x 64B)
    int* cnt1  = (int*)(W + 7680000);        //  1,280,000 ( 20000 x 64B)
    int* cnt2  = (int*)(W + 8960000);        //    256,000 (  4000 x 64B)  memset [0,9,216,000)
    int* col0  = (int*)(W + 9216000);        // 30,720,000 (120000 x 64)
    int* col1  = (int*)(W + 39936000);       //  5,120,000 ( 20000 x 64)
    int* col2  = (int*)(W + 45056000);       //  1,024,000 (  4000 x 64)
    bf16* Wst0 = (bf16*)(W + 46080000);      //     65,536 (256 x 128)
    bf16* Wnt0 = (bf16*)(W + 46145536);      //     65,536
    bf16* Wst1 = (bf16*)(W + 46211072);      //    131,072 (256 x 256)
    bf16* Wnt1 = (bf16*)(W + 46342144);      //    131,072
    bf16* Wst2 = (bf16*)(W + 46473216);      //     24,576 (48 x 256, zero-padded)
    bf16* Wnt2 = (bf16*)(W + 46497792);      //     24,576  (end 46,522,368)

    const size_t BASE = 46522368;
    // big path: + xb(102,400,000) + agg0(30,720,000) + h1(61,440,000) = 241,082,368
    const bool big = ws_size >= (size_t)242000000;
    bf16* xb   = (bf16*)(W + BASE);                                // big only
    size_t o   = BASE + (big ? 102400000 : 0);
    bf16* agg0 = (bf16*)(W + o);                                   // 30,720,000
    bf16* h1   = (bf16*)(W + o + 30720000);                        // 61,440,000
    bf16* agg1 = (bf16*)(W + BASE);                                // 10,240,000 (xb/agg0 dead)
    bf16* h2   = (bf16*)(W + BASE + 10240000);                     // 10,240,000
    bf16* agg2 = (bf16*)(W + BASE + 20480000);                     //  2,048,000

    // ---- phase 1: conversions + one-pass padded CSR ----
    hipMemsetAsync(W, 0, 9216000, stream);  // all three padded cnt arrays
    if (big) {
        int n8 = 400000 * D_IN / 8;  // 6,400,000
        convert_x<<<(n8 + 255) / 256, 256, 0, stream>>>(x, xb, n8);
    }
    wt_batch<<<(221184 + 255) / 256, 256, 0, stream>>>(Ws0, Wn0, Ws1, Wn1, Ws2, Wn2,
                                                       Wst0, Wnt0, Wst1, Wnt1, Wst2, Wnt2);
    const int ETOT = E0 + E1 + E2;
    fill_pad<<<(ETOT + 255) / 256, 256, 0, stream>>>(src0, dst0, src1, dst1, src2, dst2,
                                                     cnt0, cnt1, cnt2, col0, col1, col2);

    // ---- layer 0: 400000 -> 120000, K=128, relu ----
    if (big) {
        gather_pad_w<D_IN><<<(N1 + 3) / 4, 256, 0, stream>>>(xb, cnt0, col0, N1, agg0);
        dim3 grid((N1 + 127) / 128, 2);
        gemm_mfma<bf16, bf16, true><<<grid, 256, 0, stream>>>(xb, agg0, Wst0, Wnt0, b0, h1, N1, 256, 256, 128);
    } else {
        gather_pad_f<D_IN><<<(N1 + 3) / 4, 256, 0, stream>>>(x, cnt0, col0, N1, agg0);
        dim3 grid((N1 + 127) / 128, 2);
        gemm_mfma<float, bf16, true><<<grid, 256, 0, stream>>>(x, agg0, Wst0, Wnt0, b0, h1, N1, 256, 256, 128);
    }

    // ---- layer 1: 120000 -> 20000, K=256, relu ----
    gather_pad_w<D_HID><<<(N2 + 3) / 4, 256, 0, stream>>>(h1, cnt1, col1, N2, agg1);
    {
        dim3 grid((N2 + 127) / 128, 2);
        gemm_mfma<bf16, bf16, true><<<grid, 256, 0, stream>>>(h1, agg1, Wst1, Wnt1, b1, h2, N2, 256, 256, 256);
    }

    // ---- layer 2: 20000 -> 4000, K=256, no relu ----
    gather_pad_w<D_HID><<<(N3 + 3) / 4, 256, 0, stream>>>(h2, cnt2, col2, N3, agg2);
    {
        dim3 grid((N3 + 127) / 128, 1);
        gemm_mfma<bf16, float, false><<<grid, 256, 0, stream>>>(h2, agg2, Wst2, Wnt2, b2, out, N3, 47, 48, 256);
    }
}